// Round 3
// baseline (61.497 us; speedup 1.0000x reference)
//
#include <hip/hip_runtime.h>
#include <stdint.h>

#define B_N 16
#define C_N 64
#define O_N 64
#define H_N 128
#define W_N 128

typedef short bf16x8 __attribute__((ext_vector_type(8)));
typedef float f32x4 __attribute__((ext_vector_type(4)));
typedef unsigned short u16;
typedef u16 u16x4 __attribute__((ext_vector_type(4)));

__device__ __forceinline__ u16 f2bf(float f) {
    uint32_t u = __float_as_uint(f);
    u += 0x7FFFu + ((u >> 16) & 1u);
    return (u16)(u >> 16);
}

// Period-8 swizzle: permutation on EVERY 8-consecutive-w window (incl. the
// jsh=+-1 shifted read windows) -> b128 reads conflict-free. Staging writes
// pay ~28 cyc/store (measured R0/R1 ledger) = ~4.5us of LDS pipe — accepted:
// LDS pipe is ~40% busy, not critical path; swz2 experiment (R2) proved the
// counter doesn't respond to the analytical fix.
__device__ __forceinline__ int swz(int w) { return (w & 7) << 4; }

// Pre-gather weights into exact B-fragment order (coalesced reads):
// wf[b][ij][cs][of][l][j8] (bf16); value = weight[b][c*9+ij][o],
// c = cs*32 + (l>>4)*8 + j8,  o = of*16 + (l&15).
__global__ __launch_bounds__(256) void prep_weights(const float* __restrict__ wt,
                                                    u16* __restrict__ wf) {
    int idx = blockIdx.x * 256 + threadIdx.x;   // 16*64*9*16 = 147456 total
    int e = idx;
    int o4 = e & 15; e >>= 4;
    int ij = e % 9;  e /= 9;
    int c  = e & 63; e >>= 6;
    int b  = e;
    f32x4 v = *reinterpret_cast<const f32x4*>(
        wt + ((size_t)b * 576 + (size_t)c * 9 + ij) * 64 + o4 * 4);
    const int cs = c >> 5, lgc = (c >> 3) & 3, j8 = c & 7;
#pragma unroll
    for (int k = 0; k < 4; ++k) {
        int o = o4 * 4 + k;
        int of = o >> 4, lrc = o & 15;
        size_t dst = ((size_t)((((b * 9 + ij) * 2 + cs) * 4 + of) * 64 + lgc * 16 + lrc)) * 8 + j8;
        wf[dst] = f2bf(v[k]);
    }
}

// Main kernel v4: occupancy-doubled R1.
// 512 blocks x 512 threads (8 waves). LDS 64KB/block -> 2 blocks/CU ->
// 16 waves/CU = 4 waves/SIMD (R1 had 2/SIMD; latency-bound diagnosis).
// Each wave owns a 32(w) x 32(o) output subtile: wave_m=wid>>1 (0..3),
// wave_n=wid&1. Same 4-row strip, 4-slot circular LDS, rolling 3-deep
// weight buffer, restage of rows s=4,5 pipelined under compute.
__global__ __launch_bounds__(512, 4) void conv_main(const float* __restrict__ x,
                                                    const u16* __restrict__ wf,
                                                    const float* __restrict__ bias,
                                                    float* __restrict__ y) {
    __shared__ u16 xl[4 * 128 * 64];   // 4 row-slots x [w][c] bf16, 64KB

    // XCD-bijective swizzle: 512 wgs, 8 XCDs -> XCD j owns 2 full b's.
    const int lid = (blockIdx.x & 7) * 64 + (blockIdx.x >> 3);
    const int b = lid >> 5;
    const int h0 = (lid & 31) * 4;
    const int tid = threadIdx.x;

    const int wid = tid >> 6;
    const int l = tid & 63;
    const int wave_m = wid >> 1;              // 0..3
    const int wave_n = wid & 1;               // 0..1
    const int m0 = wave_m * 32;
    const int o0 = wave_n * 32;
    const int lr = l & 15;
    const int lg = l >> 4;

    // staging task (1 per thread per row): 32 w-quads x 16 c-quads
    const int w4 = tid & 31;
    const int cq = tid >> 5;                  // 0..15
    const float* xb = x + (size_t)b * (64 * 128 * 128);

    const u16* wfb = wf + (size_t)b * (9 * 2 * 4 * 64 * 8);

    // Rolling 3-deep weight buffer; loadw(t+2) at step t.
    bf16x8 wbuf[3][4];                         // [buf][cs*2+nf]
    auto loadw = [&](int t) {
        const int ij = t % 9;
        const u16* p = wfb + (size_t)(ij * 8 + wave_n * 2) * 512 + l * 8;
        bf16x8* d = wbuf[t % 3];
        d[0] = *reinterpret_cast<const bf16x8*>(p);          // cs0 nf0
        d[1] = *reinterpret_cast<const bf16x8*>(p + 512);    // cs0 nf1
        d[2] = *reinterpret_cast<const bf16x8*>(p + 2048);   // cs1 nf0
        d[3] = *reinterpret_cast<const bf16x8*>(p + 2560);   // cs1 nf1
    };

    loadw(0);
    loadw(1);
    const float bv0 = bias[b * 64 + o0 + lr];
    const float bv1 = bias[b * 64 + o0 + 16 + lr];

    // ---- Prologue: stage rows s=0..3 (input rows h0-1..h0+2) ----
#pragma unroll
    for (int s = 0; s < 4; ++s) {
        int hr = (h0 + s + 127) & 127;
        const float* src = xb + ((size_t)cq * 4 * 128 + hr) * 128 + w4 * 4;
        f32x4 L0 = *reinterpret_cast<const f32x4*>(src);
        f32x4 L1 = *reinterpret_cast<const f32x4*>(src + 16384);
        f32x4 L2 = *reinterpret_cast<const f32x4*>(src + 32768);
        f32x4 L3 = *reinterpret_cast<const f32x4*>(src + 49152);
#pragma unroll
        for (int j = 0; j < 4; ++j) {
            int w = w4 * 4 + j;
            u16x4 pk;
            pk.x = f2bf(L0[j]); pk.y = f2bf(L1[j]);
            pk.z = f2bf(L2[j]); pk.w = f2bf(L3[j]);
            int byte = s * 16384 + w * 128 + cq * 8;
            byte ^= swz(w);
            *reinterpret_cast<u16x4*>(reinterpret_cast<char*>(xl) + byte) = pk;
        }
    }
    __syncthreads();

    f32x4 stg[4];                             // restage hold (one row at a time)

    // ---- 4 output rows ----
#pragma unroll
    for (int r = 0; r < 4; ++r) {
        f32x4 acc[2][2];
#pragma unroll
        for (int mf = 0; mf < 2; ++mf)
#pragma unroll
            for (int nf = 0; nf < 2; ++nf)
                acc[mf][nf] = (f32x4){0.f, 0.f, 0.f, 0.f};

#pragma unroll
        for (int ij = 0; ij < 9; ++ij) {
            const int t = r * 9 + ij;
            if (t + 2 < 36) loadw(t + 2);

            // ---- restage pipeline ----
            // s=4 (input h0+3): load at r0/ij5, write->slot0 at r1/ij0
            //   (slot0 = s=0, last read in r0; barrier after r0 protects;
            //    read of s=4 starts r2, barrier after r1 intervenes)
            // s=5 (input h0+4): load at r1/ij2, write->slot1 at r2/ij5
            //   (slot1 = s=1, last read r1; read of s=5 only in r3)
            if (r == 0 && ij == 5) {
                int hr = (h0 + 3) & 127;
                const float* src = xb + ((size_t)cq * 4 * 128 + hr) * 128 + w4 * 4;
                stg[0] = *reinterpret_cast<const f32x4*>(src);
                stg[1] = *reinterpret_cast<const f32x4*>(src + 16384);
                stg[2] = *reinterpret_cast<const f32x4*>(src + 32768);
                stg[3] = *reinterpret_cast<const f32x4*>(src + 49152);
            }
            if ((r == 1 && ij == 0) || (r == 2 && ij == 5)) {
                const int slot = (r == 1) ? 0 : 1;
#pragma unroll
                for (int j = 0; j < 4; ++j) {
                    int w = w4 * 4 + j;
                    u16x4 pk;
                    pk.x = f2bf(stg[0][j]); pk.y = f2bf(stg[1][j]);
                    pk.z = f2bf(stg[2][j]); pk.w = f2bf(stg[3][j]);
                    int byte = slot * 16384 + w * 128 + cq * 8;
                    byte ^= swz(w);
                    *reinterpret_cast<u16x4*>(reinterpret_cast<char*>(xl) + byte) = pk;
                }
            }
            if (r == 1 && ij == 2) {
                int hr = (h0 + 4) & 127;
                const float* src = xb + ((size_t)cq * 4 * 128 + hr) * 128 + w4 * 4;
                stg[0] = *reinterpret_cast<const f32x4*>(src);
                stg[1] = *reinterpret_cast<const f32x4*>(src + 16384);
                stg[2] = *reinterpret_cast<const f32x4*>(src + 32768);
                stg[3] = *reinterpret_cast<const f32x4*>(src + 49152);
            }

            // ---- compute ----
            const int i = ij / 3;
            const int jsh = ij % 3 - 1;
            const int rbase = ((r + i) & 3) * 16384;
            const bf16x8* wv = wbuf[t % 3];
#pragma unroll
            for (int cs = 0; cs < 2; ++cs) {
                bf16x8 afr[2];
                const int cb = cs * 64 + lg * 16;
#pragma unroll
                for (int mf = 0; mf < 2; ++mf) {
                    int w = (m0 + mf * 16 + lr + jsh + 128) & 127;
                    int byte = rbase + w * 128 + cb;
                    byte ^= swz(w);
                    afr[mf] = *reinterpret_cast<const bf16x8*>(
                        reinterpret_cast<const char*>(xl) + byte);
                }
#pragma unroll
                for (int mf = 0; mf < 2; ++mf) {
                    acc[mf][0] = __builtin_amdgcn_mfma_f32_16x16x32_bf16(afr[mf], wv[cs * 2 + 0], acc[mf][0], 0, 0, 0);
                    acc[mf][1] = __builtin_amdgcn_mfma_f32_16x16x32_bf16(afr[mf], wv[cs * 2 + 1], acc[mf][1], 0, 0, 0);
                }
            }
        }

        // ---- Epilogue: D layout col=lane&15 (o), row=(lane>>4)*4+reg (w) ----
        const int h = h0 + r;
#pragma unroll
        for (int nf = 0; nf < 2; ++nf) {
            int o = o0 + nf * 16 + lr;
            float bv = nf ? bv1 : bv0;
#pragma unroll
            for (int mf = 0; mf < 2; ++mf) {
                int w0 = m0 + mf * 16 + lg * 4;
                float* dst = y + (((size_t)b * 64 + o) * 128 + h) * 128 + w0;
                f32x4 out;
                out[0] = acc[mf][nf][0] + bv;
                out[1] = acc[mf][nf][1] + bv;
                out[2] = acc[mf][nf][2] + bv;
                out[3] = acc[mf][nf][3] + bv;
                *reinterpret_cast<f32x4*>(dst) = out;
            }
        }
        if (r < 3) __syncthreads();
    }
}

// Correctness-insurance fallback if workspace is too small (should not trigger).
__global__ void naive_conv(const float* __restrict__ x, const float* __restrict__ wt,
                           const float* __restrict__ bias, float* __restrict__ y) {
    int w = threadIdx.x;
    int h = blockIdx.x & 127;
    int o = (blockIdx.x >> 7) & 63;
    int b = blockIdx.x >> 13;
    float s = bias[b * 64 + o];
    for (int c = 0; c < 64; ++c)
        for (int i = 0; i < 3; ++i)
            for (int j = 0; j < 3; ++j) {
                int hh = (h + i + 127) & 127;
                int ww = (w + j + 127) & 127;
                s += x[(((size_t)b * 64 + c) * 128 + hh) * 128 + ww] *
                     wt[((size_t)b * 576 + (size_t)(c * 9 + i * 3 + j)) * 64 + o];
            }
    y[(((size_t)b * 64 + o) * 128 + h) * 128 + w] = s;
}

extern "C" void kernel_launch(void* const* d_in, const int* in_sizes, int n_in,
                              void* d_out, int out_size, void* d_ws, size_t ws_size,
                              hipStream_t stream) {
    const float* x    = (const float*)d_in[0];
    const float* wt   = (const float*)d_in[1];
    const float* bias = (const float*)d_in[2];
    float* y = (float*)d_out;

    const size_t WF_ELEMS = (size_t)B_N * 9 * 2 * 4 * 64 * 8;   // 589824
    const size_t WF_BYTES = WF_ELEMS * sizeof(u16);             // 1.18 MB

    if (ws_size >= WF_BYTES) {
        u16* wf = (u16*)d_ws;
        hipLaunchKernelGGL(prep_weights, dim3(576), dim3(256), 0, stream, wt, wf);
        hipLaunchKernelGGL(conv_main, dim3(B_N * H_N / 4), dim3(512), 0, stream, x, wf, bias, y);
    } else {
        hipLaunchKernelGGL(naive_conv, dim3(B_N * O_N * H_N), dim3(128), 0, stream, x, wt, bias, y);
    }
}

// Round 4
// 39.065 us; speedup vs baseline: 1.5742x; 1.5742x over previous
//
#include <hip/hip_runtime.h>
#include <stdint.h>

#define B_N 16
#define C_N 64
#define O_N 64
#define H_N 128
#define W_N 128

typedef short bf16x8 __attribute__((ext_vector_type(8)));
typedef float f32x4 __attribute__((ext_vector_type(4)));
typedef unsigned short u16;
typedef u16 u16x4 __attribute__((ext_vector_type(4)));

__device__ __forceinline__ u16 f2bf(float f) {
    uint32_t u = __float_as_uint(f);
    u += 0x7FFFu + ((u >> 16) & 1u);
    return (u16)(u >> 16);
}

// Period-8 swizzle: permutation on EVERY 8-consecutive-w window (incl. the
// jsh=+-1 shifted read windows) -> b128 reads conflict-free. Staging writes
// pay ~28 cyc/store (R0/R1 ledger) — accepted; LDS pipe has headroom and the
// swz2 probe (R2) showed the counter doesn't respond to the analytical fix.
__device__ __forceinline__ int swz(int w) { return (w & 7) << 4; }

// Pre-gather weights into exact B-fragment order (coalesced reads):
// wf[b][ij][cs][of][l][j8] (bf16); value = weight[b][c*9+ij][o],
// c = cs*32 + (l>>4)*8 + j8,  o = of*16 + (l&15).
__global__ __launch_bounds__(256) void prep_weights(const float* __restrict__ wt,
                                                    u16* __restrict__ wf) {
    int idx = blockIdx.x * 256 + threadIdx.x;   // 16*64*9*16 = 147456 total
    int e = idx;
    int o4 = e & 15; e >>= 4;
    int ij = e % 9;  e /= 9;
    int c  = e & 63; e >>= 6;
    int b  = e;
    f32x4 v = *reinterpret_cast<const f32x4*>(
        wt + ((size_t)b * 576 + (size_t)c * 9 + ij) * 64 + o4 * 4);
    const int cs = c >> 5, lgc = (c >> 3) & 3, j8 = c & 7;
#pragma unroll
    for (int k = 0; k < 4; ++k) {
        int o = o4 * 4 + k;
        int of = o >> 4, lrc = o & 15;
        size_t dst = ((size_t)((((b * 9 + ij) * 2 + cs) * 4 + of) * 64 + lgc * 16 + lrc)) * 8 + j8;
        wf[dst] = f2bf(v[k]);
    }
}

// Main kernel v5: weights resident in LDS (72 KB, staged once per block) ->
// inner loop is pure ds_read + MFMA, no VMEM, no weight register buffer.
// Grid 256 (8-row strips), 512 threads (8 waves, each 32px x 32o), 136 KB
// dynamic LDS -> 1 block/CU, 2 waves/SIMD (the level R1 validated; R3 showed
// pushing waves/SIMD does not pay). 4-slot circular x buffer, restage 1 row
// per row-iteration (load at ij2, ds_write at ij6, barrier at row end).
__global__ __launch_bounds__(512, 2) void conv_main(const float* __restrict__ x,
                                                    const u16* __restrict__ wf,
                                                    const float* __restrict__ bias,
                                                    float* __restrict__ y) {
    extern __shared__ u16 smem[];
    u16* xl = smem;            // 4 slots x [w][c] bf16 = 32768 u16 (64 KB), swz
    u16* wl = smem + 32768;    // weight fragments, 36864 u16 (72 KB)

    // XCD-bijective swizzle: 256 wgs, 8 XCDs, chunk 32 -> XCD j owns 2 full b's.
    const int lid = (blockIdx.x & 7) * 32 + (blockIdx.x >> 3);
    const int b   = lid >> 4;
    const int h0  = (lid & 15) * 8;
    const int tid = threadIdx.x;
    const int wid = tid >> 6;
    const int l   = tid & 63;
    const int wave_m = wid >> 1;              // 0..3 -> 32-px band
    const int wave_n = wid & 1;               // 0..1 -> 32-o band
    const int m0 = wave_m * 32;
    const int o0 = wave_n * 32;
    const int lr = l & 15;
    const int lg = l >> 4;

    // staging task: 32 w-quads x 16 c-quads = 512 threads, full row per pass
    const int w4 = tid & 31;
    const int cq = tid >> 5;                  // 0..15
    const float* xb = x + (size_t)b * (64 * 128 * 128);
    const u16* wfb  = wf + (size_t)b * 36864;

    // ---- weights -> LDS, once: 73728 B = 512 thr x 9 x 16 B (coalesced,
    //      conflict-free stride-16 ds_writes) ----
#pragma unroll
    for (int k = 0; k < 9; ++k) {
        bf16x8 v = *reinterpret_cast<const bf16x8*>(wfb + k * 4096 + tid * 8);
        *reinterpret_cast<bf16x8*>(wl + k * 4096 + tid * 8) = v;
    }

    const float bv0 = bias[b * 64 + o0 + lr];
    const float bv1 = bias[b * 64 + o0 + 16 + lr];

    auto ldrow = [&](int s, f32x4* d) {
        int hr = (h0 + s + 127) & 127;        // input row h0 + s - 1 (wrap)
        const float* src = xb + ((size_t)cq * 4 * 128 + hr) * 128 + w4 * 4;
        d[0] = *reinterpret_cast<const f32x4*>(src);
        d[1] = *reinterpret_cast<const f32x4*>(src + 16384);
        d[2] = *reinterpret_cast<const f32x4*>(src + 32768);
        d[3] = *reinterpret_cast<const f32x4*>(src + 49152);
    };
    auto wrrow = [&](int s, const f32x4* d) {
#pragma unroll
        for (int j = 0; j < 4; ++j) {
            int w = w4 * 4 + j;
            u16x4 pk;
            pk.x = f2bf(d[0][j]); pk.y = f2bf(d[1][j]);
            pk.z = f2bf(d[2][j]); pk.w = f2bf(d[3][j]);
            int byte = (s & 3) * 16384 + w * 128 + cq * 8;
            byte ^= swz(w);
            *reinterpret_cast<u16x4*>(reinterpret_cast<char*>(xl) + byte) = pk;
        }
    };

    // ---- Prologue: stage s=0..2 (input rows h0-1..h0+1) ----
    f32x4 st[4];
#pragma unroll
    for (int s = 0; s < 3; ++s) { ldrow(s, st); wrrow(s, st); }
    __syncthreads();

    // ---- 8 output rows. Row r reads staged s=r..r+2 (slots s&3); slot
    //      (r+3)&3 is dead (held s=r-1) -> restage s=r+3 into it during row r.
#pragma unroll 1
    for (int r = 0; r < 8; ++r) {
        f32x4 acc[2][2];
#pragma unroll
        for (int mf = 0; mf < 2; ++mf)
#pragma unroll
            for (int nf = 0; nf < 2; ++nf)
                acc[mf][nf] = (f32x4){0.f, 0.f, 0.f, 0.f};

#pragma unroll
        for (int ij = 0; ij < 9; ++ij) {
            if (ij == 2 && r < 7) ldrow(r + 3, st);   // HBM latency hides under MFMA
            if (ij == 6 && r < 7) wrrow(r + 3, st);   // write before row-end barrier

            const int i = ij / 3;
            const int jsh = ij % 3 - 1;
            const int rbase = ((r + i) & 3) * 16384;
#pragma unroll
            for (int cs = 0; cs < 2; ++cs) {
                const int cb = cs * 64 + lg * 16;
                bf16x8 afr[2], bfr[2];
#pragma unroll
                for (int nf = 0; nf < 2; ++nf)
                    bfr[nf] = *reinterpret_cast<const bf16x8*>(
                        wl + (size_t)(((ij * 2 + cs) * 4 + wave_n * 2 + nf) * 64 + l) * 8);
#pragma unroll
                for (int mf = 0; mf < 2; ++mf) {
                    int w = (m0 + mf * 16 + lr + jsh + 128) & 127;
                    int byte = rbase + w * 128 + cb;
                    byte ^= swz(w);
                    afr[mf] = *reinterpret_cast<const bf16x8*>(
                        reinterpret_cast<const char*>(xl) + byte);
                }
#pragma unroll
                for (int mf = 0; mf < 2; ++mf) {
                    acc[mf][0] = __builtin_amdgcn_mfma_f32_16x16x32_bf16(afr[mf], bfr[0], acc[mf][0], 0, 0, 0);
                    acc[mf][1] = __builtin_amdgcn_mfma_f32_16x16x32_bf16(afr[mf], bfr[1], acc[mf][1], 0, 0, 0);
                }
            }
        }

        // ---- Epilogue: D layout col=lane&15 (o), row=(lane>>4)*4+reg (w) ----
        const int h = h0 + r;
#pragma unroll
        for (int nf = 0; nf < 2; ++nf) {
            int o = o0 + nf * 16 + lr;
            float bv = nf ? bv1 : bv0;
#pragma unroll
            for (int mf = 0; mf < 2; ++mf) {
                int w0 = m0 + mf * 16 + lg * 4;
                float* dst = y + (((size_t)b * 64 + o) * 128 + h) * 128 + w0;
                f32x4 out;
                out[0] = acc[mf][nf][0] + bv;
                out[1] = acc[mf][nf][1] + bv;
                out[2] = acc[mf][nf][2] + bv;
                out[3] = acc[mf][nf][3] + bv;
                *reinterpret_cast<f32x4*>(dst) = out;
            }
        }
        if (r < 7) __syncthreads();
    }
}

// Correctness-insurance fallback if workspace is too small (should not trigger).
__global__ void naive_conv(const float* __restrict__ x, const float* __restrict__ wt,
                           const float* __restrict__ bias, float* __restrict__ y) {
    int w = threadIdx.x;
    int h = blockIdx.x & 127;
    int o = (blockIdx.x >> 7) & 63;
    int b = blockIdx.x >> 13;
    float s = bias[b * 64 + o];
    for (int c = 0; c < 64; ++c)
        for (int i = 0; i < 3; ++i)
            for (int j = 0; j < 3; ++j) {
                int hh = (h + i + 127) & 127;
                int ww = (w + j + 127) & 127;
                s += x[(((size_t)b * 64 + c) * 128 + hh) * 128 + ww] *
                     wt[((size_t)b * 576 + (size_t)(c * 9 + i * 3 + j)) * 64 + o];
            }
    y[(((size_t)b * 64 + o) * 128 + h) * 128 + w] = s;
}

extern "C" void kernel_launch(void* const* d_in, const int* in_sizes, int n_in,
                              void* d_out, int out_size, void* d_ws, size_t ws_size,
                              hipStream_t stream) {
    const float* x    = (const float*)d_in[0];
    const float* wt   = (const float*)d_in[1];
    const float* bias = (const float*)d_in[2];
    float* y = (float*)d_out;

    const size_t WF_ELEMS = (size_t)B_N * 9 * 2 * 4 * 64 * 8;   // 589824
    const size_t WF_BYTES = WF_ELEMS * sizeof(u16);             // 1.18 MB
    const int DYN_LDS = 4 * 128 * 64 * 2 + 9 * 2 * 4 * 64 * 8 * 2;  // 139264 B

    static int attr_done = 0;
    if (!attr_done) {
        (void)hipFuncSetAttribute(reinterpret_cast<const void*>(conv_main),
                                  hipFuncAttributeMaxDynamicSharedMemorySize, DYN_LDS);
        attr_done = 1;
    }

    if (ws_size >= WF_BYTES) {
        u16* wf = (u16*)d_ws;
        hipLaunchKernelGGL(prep_weights, dim3(576), dim3(256), 0, stream, wt, wf);
        hipLaunchKernelGGL(conv_main, dim3(B_N * H_N / 8), dim3(512), DYN_LDS, stream, x, wf, bias, y);
    } else {
        hipLaunchKernelGGL(naive_conv, dim3(B_N * O_N * H_N), dim3(128), 0, stream, x, wt, bias, y);
    }
}

// Round 5
// 38.789 us; speedup vs baseline: 1.5854x; 1.0071x over previous
//
#include <hip/hip_runtime.h>
#include <stdint.h>

#define B_N 16
#define C_N 64
#define O_N 64
#define H_N 128
#define W_N 128

typedef short bf16x8 __attribute__((ext_vector_type(8)));
typedef float f32x4 __attribute__((ext_vector_type(4)));
typedef unsigned short u16;
typedef u16 u16x4 __attribute__((ext_vector_type(4)));

__device__ __forceinline__ u16 f2bf(float f) {
    uint32_t u = __float_as_uint(f);
    u += 0x7FFFu + ((u >> 16) & 1u);
    return (u16)(u >> 16);
}

// Period-8 swizzle: permutation on EVERY 8-consecutive-w window (incl. the
// jsh=+-1 shifted read windows) -> b128 reads conflict-free. Staging writes
// pay ~28 cyc/store (R0/R1 ledger) — accepted; swz2 probe (R2) showed the
// counter doesn't respond to the analytical fix.
__device__ __forceinline__ int swz(int w) { return (w & 7) << 4; }

// Pre-gather weights into exact B-fragment order (coalesced reads):
// wf[b][ij][cs][of][l][j8] (bf16); value = weight[b][c*9+ij][o],
// c = cs*32 + (l>>4)*8 + j8,  o = of*16 + (l&15).
__global__ __launch_bounds__(256) void prep_weights(const float* __restrict__ wt,
                                                    u16* __restrict__ wf) {
    int idx = blockIdx.x * 256 + threadIdx.x;   // 16*64*9*16 = 147456 total
    int e = idx;
    int o4 = e & 15; e >>= 4;
    int ij = e % 9;  e /= 9;
    int c  = e & 63; e >>= 6;
    int b  = e;
    f32x4 v = *reinterpret_cast<const f32x4*>(
        wt + ((size_t)b * 576 + (size_t)c * 9 + ij) * 64 + o4 * 4);
    const int cs = c >> 5, lgc = (c >> 3) & 3, j8 = c & 7;
#pragma unroll
    for (int k = 0; k < 4; ++k) {
        int o = o4 * 4 + k;
        int of = o >> 4, lrc = o & 15;
        size_t dst = ((size_t)((((b * 9 + ij) * 2 + cs) * 4 + of) * 64 + lgc * 16 + lrc)) * 8 + j8;
        wf[dst] = f2bf(v[k]);
    }
}

// Main kernel v6: v5 chassis (8-row strips, grid 256, 512 threads, 4-slot
// circular x buffer in 64KB static LDS) but B-fragments live in REGISTERS,
// loaded once per block (R4 ledger: LDS B-re-reads were ~50% of LDS-pipe
// time, 8x re-reads of loop-invariant data). wreg = 144 VGPRs; (512,2)
// gives the 256-VGPR budget; steady-state need ~190 -> no spill (tripwire:
// WRITE_SIZE > 66 MB). Inner loop is now A-ds_read + MFMA only.
__global__ __launch_bounds__(512, 2) void conv_main(const float* __restrict__ x,
                                                    const u16* __restrict__ wf,
                                                    const float* __restrict__ bias,
                                                    float* __restrict__ y) {
    __shared__ u16 xl[4 * 128 * 64];   // 4 slots x [w][c] bf16 = 64 KB, swz

    // XCD-bijective swizzle: 256 wgs, 8 XCDs, chunk 32 -> XCD j owns 2 full b's.
    const int lid = (blockIdx.x & 7) * 32 + (blockIdx.x >> 3);
    const int b   = lid >> 4;
    const int h0  = (lid & 15) * 8;
    const int tid = threadIdx.x;
    const int wid = tid >> 6;
    const int l   = tid & 63;
    const int wave_m = wid >> 1;              // 0..3 -> 32-px band
    const int wave_n = wid & 1;               // 0..1 -> 32-o band
    const int m0 = wave_m * 32;
    const int o0 = wave_n * 32;
    const int lr = l & 15;
    const int lg = l >> 4;

    // staging task: 32 w-quads x 16 c-quads = 512 threads, full row per pass
    const int w4 = tid & 31;
    const int cq = tid >> 5;                  // 0..15
    const float* xb = x + (size_t)b * (64 * 128 * 128);
    const u16* wfb  = wf + (size_t)b * 36864;

    auto ldrow = [&](int s, f32x4* d) {
        int hr = (h0 + s + 127) & 127;        // input row h0 + s - 1 (wrap)
        const float* src = xb + ((size_t)cq * 4 * 128 + hr) * 128 + w4 * 4;
        d[0] = *reinterpret_cast<const f32x4*>(src);
        d[1] = *reinterpret_cast<const f32x4*>(src + 16384);
        d[2] = *reinterpret_cast<const f32x4*>(src + 32768);
        d[3] = *reinterpret_cast<const f32x4*>(src + 49152);
    };
    auto wrrow = [&](int s, const f32x4* d) {
#pragma unroll
        for (int j = 0; j < 4; ++j) {
            int w = w4 * 4 + j;
            u16x4 pk;
            pk.x = f2bf(d[0][j]); pk.y = f2bf(d[1][j]);
            pk.z = f2bf(d[2][j]); pk.w = f2bf(d[3][j]);
            int byte = (s & 3) * 16384 + w * 128 + cq * 8;
            byte ^= swz(w);
            *reinterpret_cast<u16x4*>(reinterpret_cast<char*>(xl) + byte) = pk;
        }
    };

    // ---- Prologue. VMEM issue order matters: x-row loads FIRST, weight
    // loads second -> wrrow's vmcnt waits only drain the (older) x loads;
    // weight results are first needed after the barrier (row 0 MFMAs). ----
    f32x4 s0[4], s1[4], s2[4];
    ldrow(0, s0); ldrow(1, s1); ldrow(2, s2);

    bf16x8 wreg[9][2][2];                     // [ij][cs][nf] = 144 VGPRs
#pragma unroll
    for (int ij = 0; ij < 9; ++ij)
#pragma unroll
        for (int cs = 0; cs < 2; ++cs)
#pragma unroll
            for (int nf = 0; nf < 2; ++nf)
                wreg[ij][cs][nf] = *reinterpret_cast<const bf16x8*>(
                    wfb + (size_t)(((ij * 2 + cs) * 4 + wave_n * 2 + nf) * 64 + l) * 8);

    const float bv0 = bias[b * 64 + o0 + lr];
    const float bv1 = bias[b * 64 + o0 + 16 + lr];

    wrrow(0, s0); wrrow(1, s1); wrrow(2, s2);
    __syncthreads();

    // ---- 8 output rows. Row r reads staged s=r..r+2 (slots s&3); slot
    //      (r+3)&3 is dead (held s=r-1) -> restage s=r+3 into it during row r.
    f32x4 st[4];
#pragma unroll 1
    for (int r = 0; r < 8; ++r) {
        f32x4 acc[2][2];
#pragma unroll
        for (int mf = 0; mf < 2; ++mf)
#pragma unroll
            for (int nf = 0; nf < 2; ++nf)
                acc[mf][nf] = (f32x4){0.f, 0.f, 0.f, 0.f};

#pragma unroll
        for (int ij = 0; ij < 9; ++ij) {
            if (ij == 2 && r < 7) ldrow(r + 3, st);   // HBM latency hides under MFMA
            if (ij == 6 && r < 7) wrrow(r + 3, st);   // write before row-end barrier

            const int i = ij / 3;
            const int jsh = ij % 3 - 1;
            const int rbase = ((r + i) & 3) * 16384;
#pragma unroll
            for (int cs = 0; cs < 2; ++cs) {
                const int cb = cs * 64 + lg * 16;
                bf16x8 afr[2];
#pragma unroll
                for (int mf = 0; mf < 2; ++mf) {
                    int w = (m0 + mf * 16 + lr + jsh + 128) & 127;
                    int byte = rbase + w * 128 + cb;
                    byte ^= swz(w);
                    afr[mf] = *reinterpret_cast<const bf16x8*>(
                        reinterpret_cast<const char*>(xl) + byte);
                }
#pragma unroll
                for (int mf = 0; mf < 2; ++mf) {
                    acc[mf][0] = __builtin_amdgcn_mfma_f32_16x16x32_bf16(afr[mf], wreg[ij][cs][0], acc[mf][0], 0, 0, 0);
                    acc[mf][1] = __builtin_amdgcn_mfma_f32_16x16x32_bf16(afr[mf], wreg[ij][cs][1], acc[mf][1], 0, 0, 0);
                }
            }
        }

        // ---- Epilogue: D layout col=lane&15 (o), row=(lane>>4)*4+reg (w) ----
        const int h = h0 + r;
#pragma unroll
        for (int nf = 0; nf < 2; ++nf) {
            int o = o0 + nf * 16 + lr;
            float bv = nf ? bv1 : bv0;
#pragma unroll
            for (int mf = 0; mf < 2; ++mf) {
                int w0 = m0 + mf * 16 + lg * 4;
                float* dst = y + (((size_t)b * 64 + o) * 128 + h) * 128 + w0;
                f32x4 out;
                out[0] = acc[mf][nf][0] + bv;
                out[1] = acc[mf][nf][1] + bv;
                out[2] = acc[mf][nf][2] + bv;
                out[3] = acc[mf][nf][3] + bv;
                *reinterpret_cast<f32x4*>(dst) = out;
            }
        }
        if (r < 7) __syncthreads();
    }
}

// Correctness-insurance fallback if workspace is too small (should not trigger).
__global__ void naive_conv(const float* __restrict__ x, const float* __restrict__ wt,
                           const float* __restrict__ bias, float* __restrict__ y) {
    int w = threadIdx.x;
    int h = blockIdx.x & 127;
    int o = (blockIdx.x >> 7) & 63;
    int b = blockIdx.x >> 13;
    float s = bias[b * 64 + o];
    for (int c = 0; c < 64; ++c)
        for (int i = 0; i < 3; ++i)
            for (int j = 0; j < 3; ++j) {
                int hh = (h + i + 127) & 127;
                int ww = (w + j + 127) & 127;
                s += x[(((size_t)b * 64 + c) * 128 + hh) * 128 + ww] *
                     wt[((size_t)b * 576 + (size_t)(c * 9 + i * 3 + j)) * 64 + o];
            }
    y[(((size_t)b * 64 + o) * 128 + h) * 128 + w] = s;
}

extern "C" void kernel_launch(void* const* d_in, const int* in_sizes, int n_in,
                              void* d_out, int out_size, void* d_ws, size_t ws_size,
                              hipStream_t stream) {
    const float* x    = (const float*)d_in[0];
    const float* wt   = (const float*)d_in[1];
    const float* bias = (const float*)d_in[2];
    float* y = (float*)d_out;

    const size_t WF_ELEMS = (size_t)B_N * 9 * 2 * 4 * 64 * 8;   // 589824
    const size_t WF_BYTES = WF_ELEMS * sizeof(u16);             // 1.18 MB

    if (ws_size >= WF_BYTES) {
        u16* wf = (u16*)d_ws;
        hipLaunchKernelGGL(prep_weights, dim3(576), dim3(256), 0, stream, wt, wf);
        hipLaunchKernelGGL(conv_main, dim3(B_N * H_N / 8), dim3(512), 0, stream, x, wf, bias, y);
    } else {
        hipLaunchKernelGGL(naive_conv, dim3(B_N * O_N * H_N), dim3(128), 0, stream, x, wt, bias, y);
    }
}

// Round 6
// 38.302 us; speedup vs baseline: 1.6056x; 1.0127x over previous
//
#include <hip/hip_runtime.h>
#include <stdint.h>

#define B_N 16
#define C_N 64
#define O_N 64
#define H_N 128
#define W_N 128

typedef short bf16x8 __attribute__((ext_vector_type(8)));
typedef float f32x4 __attribute__((ext_vector_type(4)));
typedef unsigned short u16;
typedef u16 u16x4 __attribute__((ext_vector_type(4)));

__device__ __forceinline__ u16 f2bf(float f) {
    uint32_t u = __float_as_uint(f);
    u += 0x7FFFu + ((u >> 16) & 1u);
    return (u16)(u >> 16);
}

// Period-8 swizzle: conflict-free b128 reads on every 8-w window (incl. the
// jsh=+-1 shifted windows). Staging writes pay ~28 cyc/store (R0/R1 ledger)
// — accepted (LDS pipe not the bottleneck; proven by R4->R5 flatness).
__device__ __forceinline__ int swz(int w) { return (w & 7) << 4; }

// Pre-gather weights into exact B-fragment order (coalesced reads):
// wf[b][ij][cs][of][l][j8] (bf16); value = weight[b][c*9+ij][o],
// c = cs*32 + (l>>4)*8 + j8,  o = of*16 + (l&15).
__global__ __launch_bounds__(256) void prep_weights(const float* __restrict__ wt,
                                                    u16* __restrict__ wf) {
    int idx = blockIdx.x * 256 + threadIdx.x;   // 16*64*9*16 = 147456 total
    int e = idx;
    int o4 = e & 15; e >>= 4;
    int ij = e % 9;  e /= 9;
    int c  = e & 63; e >>= 6;
    int b  = e;
    f32x4 v = *reinterpret_cast<const f32x4*>(
        wt + ((size_t)b * 576 + (size_t)c * 9 + ij) * 64 + o4 * 4);
    const int cs = c >> 5, lgc = (c >> 3) & 3, j8 = c & 7;
#pragma unroll
    for (int k = 0; k < 4; ++k) {
        int o = o4 * 4 + k;
        int of = o >> 4, lrc = o & 15;
        size_t dst = ((size_t)((((b * 9 + ij) * 2 + cs) * 4 + of) * 64 + lgc * 16 + lrc)) * 8 + j8;
        wf[dst] = f2bf(v[k]);
    }
}

// Main kernel v7: v6 chassis (8-row strips, grid 256, 512 thr, wreg B-frags)
// with a DEEP staging pipeline:
//  - 6 LDS row-slots (96 KB; still 1 block/CU, 2 waves/SIMD).
//  - Row r: ds_write s=r+4 at ij0 (data loaded during row r-1 -> ~1.4us
//    latency budget instead of 0.64us burst), global_load s=r+5 at ij3.
//  - Slot distance >=2 rows in both hazard directions -> barrier only every
//    2 rows (after rows 1,3,5): halves the vmcnt(0) barrier drains.
__global__ __launch_bounds__(512, 2) void conv_main(const float* __restrict__ x,
                                                    const u16* __restrict__ wf,
                                                    const float* __restrict__ bias,
                                                    float* __restrict__ y) {
    __shared__ u16 xl[6 * 128 * 64];   // 6 slots x [w][c] bf16 = 96 KB, swz

    // XCD-bijective swizzle: 256 wgs, 8 XCDs, chunk 32 -> XCD j owns 2 full b's.
    const int lid = (blockIdx.x & 7) * 32 + (blockIdx.x >> 3);
    const int b   = lid >> 4;
    const int h0  = (lid & 15) * 8;
    const int tid = threadIdx.x;
    const int wid = tid >> 6;
    const int l   = tid & 63;
    const int wave_m = wid >> 1;              // 0..3 -> 32-px band
    const int wave_n = wid & 1;               // 0..1 -> 32-o band
    const int m0 = wave_m * 32;
    const int o0 = wave_n * 32;
    const int lr = l & 15;
    const int lg = l >> 4;

    // staging task: 32 w-quads x 16 c-quads = 512 threads, full row per pass
    const int w4 = tid & 31;
    const int cq = tid >> 5;                  // 0..15
    const float* xb = x + (size_t)b * (64 * 128 * 128);
    const u16* wfb  = wf + (size_t)b * 36864;

    auto ldrow = [&](int s, f32x4* d) {
        int hr = (h0 + s + 127) & 127;        // input row h0 + s - 1 (wrap)
        const float* src = xb + ((size_t)cq * 4 * 128 + hr) * 128 + w4 * 4;
        d[0] = *reinterpret_cast<const f32x4*>(src);
        d[1] = *reinterpret_cast<const f32x4*>(src + 16384);
        d[2] = *reinterpret_cast<const f32x4*>(src + 32768);
        d[3] = *reinterpret_cast<const f32x4*>(src + 49152);
    };
    auto wrrow = [&](int slot, const f32x4* d) {   // slot = staged-row % 6
#pragma unroll
        for (int j = 0; j < 4; ++j) {
            int w = w4 * 4 + j;
            u16x4 pk;
            pk.x = f2bf(d[0][j]); pk.y = f2bf(d[1][j]);
            pk.z = f2bf(d[2][j]); pk.w = f2bf(d[3][j]);
            int byte = slot * 16384 + w * 128 + cq * 8;
            byte ^= swz(w);
            *reinterpret_cast<u16x4*>(reinterpret_cast<char*>(xl) + byte) = pk;
        }
    };

    // ---- Prologue: x loads FIRST, then weights (vmcnt-expressible order),
    //      stage s=0..3 into slots 0..3, preload s=4 into regs ----
    f32x4 s0[4], s1[4], s2[4], st[4];
    ldrow(0, s0); ldrow(1, s1); ldrow(2, s2);

    bf16x8 wreg[9][2][2];                     // [ij][cs][nf] = 144 VGPRs
#pragma unroll
    for (int ij = 0; ij < 9; ++ij)
#pragma unroll
        for (int cs = 0; cs < 2; ++cs)
#pragma unroll
            for (int nf = 0; nf < 2; ++nf)
                wreg[ij][cs][nf] = *reinterpret_cast<const bf16x8*>(
                    wfb + (size_t)(((ij * 2 + cs) * 4 + wave_n * 2 + nf) * 64 + l) * 8);

    const float bv0 = bias[b * 64 + o0 + lr];
    const float bv1 = bias[b * 64 + o0 + 16 + lr];

    wrrow(0, s0); wrrow(1, s1); wrrow(2, s2);
    ldrow(3, s0); ldrow(4, st);               // s4 stays in regs for row 0
    wrrow(3, s0);
    __syncthreads();

    // ---- 8 output rows; row r reads slots (r..r+2)%6 ----
    int slA = 0;                              // r % 6, tracked incrementally
#pragma unroll 1
    for (int r = 0; r < 8; ++r) {
        const int slB = (slA + 1 == 6) ? 0 : slA + 1;
        const int slC = (slB + 1 == 6) ? 0 : slB + 1;
        const int slW = (slC + 2 >= 6) ? slC + 2 - 6 : slC + 2;   // (r+4)%6
        const int base0 = slA * 16384, base1 = slB * 16384, base2 = slC * 16384;

        f32x4 acc[2][2];
#pragma unroll
        for (int mf = 0; mf < 2; ++mf)
#pragma unroll
            for (int nf = 0; nf < 2; ++nf)
                acc[mf][nf] = (f32x4){0.f, 0.f, 0.f, 0.f};

#pragma unroll
        for (int ij = 0; ij < 9; ++ij) {
            if (ij == 0 && r < 6) wrrow(slW, st);     // data loaded last row
            if (ij == 3 && r < 5) ldrow(r + 5, st);   // consumed next row

            const int i = ij / 3;
            const int jsh = ij % 3 - 1;
            const int rbase = (i == 0) ? base0 : (i == 1) ? base1 : base2;
#pragma unroll
            for (int cs = 0; cs < 2; ++cs) {
                const int cb = cs * 64 + lg * 16;
                bf16x8 afr[2];
#pragma unroll
                for (int mf = 0; mf < 2; ++mf) {
                    int w = (m0 + mf * 16 + lr + jsh + 128) & 127;
                    int byte = rbase + w * 128 + cb;
                    byte ^= swz(w);
                    afr[mf] = *reinterpret_cast<const bf16x8*>(
                        reinterpret_cast<const char*>(xl) + byte);
                }
#pragma unroll
                for (int mf = 0; mf < 2; ++mf) {
                    acc[mf][0] = __builtin_amdgcn_mfma_f32_16x16x32_bf16(afr[mf], wreg[ij][cs][0], acc[mf][0], 0, 0, 0);
                    acc[mf][1] = __builtin_amdgcn_mfma_f32_16x16x32_bf16(afr[mf], wreg[ij][cs][1], acc[mf][1], 0, 0, 0);
                }
            }
        }

        // ---- Epilogue: D layout col=lane&15 (o), row=(lane>>4)*4+reg (w) ----
        const int h = h0 + r;
#pragma unroll
        for (int nf = 0; nf < 2; ++nf) {
            int o = o0 + nf * 16 + lr;
            float bv = nf ? bv1 : bv0;
#pragma unroll
            for (int mf = 0; mf < 2; ++mf) {
                int w0 = m0 + mf * 16 + lg * 4;
                float* dst = y + (((size_t)b * 64 + o) * 128 + h) * 128 + w0;
                f32x4 out;
                out[0] = acc[mf][nf][0] + bv;
                out[1] = acc[mf][nf][1] + bv;
                out[2] = acc[mf][nf][2] + bv;
                out[3] = acc[mf][nf][3] + bv;
                *reinterpret_cast<f32x4*>(dst) = out;
            }
        }

        // Barrier every 2 rows (after rows 1,3,5). Hazard ledger: a slot
        // written at row r is first read at row r+2 and last-read-before-
        // overwrite at row r-2 -> one barrier inside each 2-row window in
        // both directions suffices (checked per slot for r=0..7).
        if ((r & 1) && r < 7) __syncthreads();
        slA = slB;
    }
}

// Correctness-insurance fallback if workspace is too small (should not trigger).
__global__ void naive_conv(const float* __restrict__ x, const float* __restrict__ wt,
                           const float* __restrict__ bias, float* __restrict__ y) {
    int w = threadIdx.x;
    int h = blockIdx.x & 127;
    int o = (blockIdx.x >> 7) & 63;
    int b = blockIdx.x >> 13;
    float s = bias[b * 64 + o];
    for (int c = 0; c < 64; ++c)
        for (int i = 0; i < 3; ++i)
            for (int j = 0; j < 3; ++j) {
                int hh = (h + i + 127) & 127;
                int ww = (w + j + 127) & 127;
                s += x[(((size_t)b * 64 + c) * 128 + hh) * 128 + ww] *
                     wt[((size_t)b * 576 + (size_t)(c * 9 + i * 3 + j)) * 64 + o];
            }
    y[(((size_t)b * 64 + o) * 128 + h) * 128 + w] = s;
}

extern "C" void kernel_launch(void* const* d_in, const int* in_sizes, int n_in,
                              void* d_out, int out_size, void* d_ws, size_t ws_size,
                              hipStream_t stream) {
    const float* x    = (const float*)d_in[0];
    const float* wt   = (const float*)d_in[1];
    const float* bias = (const float*)d_in[2];
    float* y = (float*)d_out;

    const size_t WF_ELEMS = (size_t)B_N * 9 * 2 * 4 * 64 * 8;   // 589824
    const size_t WF_BYTES = WF_ELEMS * sizeof(u16);             // 1.18 MB

    if (ws_size >= WF_BYTES) {
        u16* wf = (u16*)d_ws;
        hipLaunchKernelGGL(prep_weights, dim3(576), dim3(256), 0, stream, wt, wf);
        hipLaunchKernelGGL(conv_main, dim3(B_N * H_N / 8), dim3(512), 0, stream, x, wf, bias, y);
    } else {
        hipLaunchKernelGGL(naive_conv, dim3(B_N * O_N * H_N), dim3(128), 0, stream, x, wt, bias, y);
    }
}